// Round 21
// baseline (312.422 us; speedup 1.0000x reference)
//
#include <hip/hip_runtime.h>
#include <cstdint>

// MultiheadRCDA: N=8, L=300, HH=WW=96, E=256, NH=8, HD=32
// Round 21: attn v6 — block=(bn,h/4): V read ONCE chip-wide (189->37.7MB
// issued). Waves 0-5 stage V h-steps (3-buffer, counted vmcnt, raw barriers);
// wcs+Vs prologue drained by one __syncthreads; r16-shape stores to part[hq].
// Means+cvt merged into one homogeneous kernel. Rest = r20.

typedef __attribute__((ext_vector_type(8))) short short8v;  // bf16x8 MFMA frag
typedef __attribute__((ext_vector_type(4))) short short4v;  // 8B packed bf16
typedef __attribute__((ext_vector_type(4))) float f32x4;

#define SCALE_Q 0.17677669529663687f  // 32^-0.5

#define GLL16(gp, lp)                                                   \
  __builtin_amdgcn_global_load_lds(                                     \
      (const __attribute__((address_space(1))) void*)(gp),              \
      (__attribute__((address_space(3))) void*)(lp), 16, 0, 0)

__device__ __forceinline__ unsigned short f2bf(float x) {
  unsigned int u = __builtin_bit_cast(unsigned int, x);
  u += 0x7FFFu + ((u >> 16) & 1u);
  return (unsigned short)(u >> 16);
}

__device__ __forceinline__ unsigned int cvtpk(float a, float b) {
  unsigned int r;
  asm("v_cvt_pk_bf16_f32 %0, %1, %2" : "=v"(r) : "v"(a), "v"(b));
  return r;
}

__device__ __forceinline__ short8v pack8cvt(const f32x4& lo, const f32x4& hi) {
  union { short8v s; unsigned int u[4]; } z;
  z.u[0] = cvtpk(lo[0], lo[1]);
  z.u[1] = cvtpk(lo[2], lo[3]);
  z.u[2] = cvtpk(hi[0], hi[1]);
  z.u[3] = cvtpk(hi[2], hi[3]);
  return z.s;
}

__device__ __forceinline__ short4v pack4cvt(float a, float b, float c, float d) {
  union { short4v s; unsigned int u[2]; } z;
  z.u[0] = cvtpk(a, b);
  z.u[1] = cvtpk(c, d);
  return z.s;
}

__device__ __forceinline__ short8v pack8(const float4& fa, const float4& fb) {
  short8v v;
  v[0] = (short)f2bf(fa.x); v[1] = (short)f2bf(fa.y);
  v[2] = (short)f2bf(fa.z); v[3] = (short)f2bf(fa.w);
  v[4] = (short)f2bf(fb.x); v[5] = (short)f2bf(fb.y);
  v[6] = (short)f2bf(fb.z); v[7] = (short)f2bf(fb.w);
  return v;
}

// ---------------- means (h + w) + weight-convert, one homogeneous kernel ----
__global__ __launch_bounds__(256) void means_kernel(
    const float* __restrict__ key_row, const float* __restrict__ key_col,
    float* __restrict__ krm, float* __restrict__ kcm,
    const float* __restrict__ w_in, const float* __restrict__ w_out,
    short* __restrict__ Wb) {
  __shared__ float4 part[256];
  int id = blockIdx.x;
  int t = threadIdx.x, e4 = t & 63, q4 = t >> 6;
  if (id < 768) {  // mean over h -> krm[b][w][e]
    int bw = id;
    int b = bw / 96, w = bw - b * 96;
    const float4* p = (const float4*)(key_row + ((size_t)b * 9216 + w) * 256) +
                      e4 + (size_t)q4 * 24 * 6144;
    float4 s = {0.f, 0.f, 0.f, 0.f};
#pragma unroll
    for (int i = 0; i < 24; ++i) {
      float4 v = p[(size_t)i * 6144];
      s.x += v.x; s.y += v.y; s.z += v.z; s.w += v.w;
    }
    part[t] = s;
    __syncthreads();
    if (t < 64) {
      float4 a = part[t], c = part[t + 64], d = part[t + 128], e = part[t + 192];
      float4 o;
      o.x = (a.x + c.x + d.x + e.x) * (1.f / 96.f);
      o.y = (a.y + c.y + d.y + e.y) * (1.f / 96.f);
      o.z = (a.z + c.z + d.z + e.z) * (1.f / 96.f);
      o.w = (a.w + c.w + d.w + e.w) * (1.f / 96.f);
      ((float4*)krm)[(size_t)bw * 64 + t] = o;
    }
    // weight-convert tail (768*512 = 393216)
#pragma unroll
    for (int k = 0; k < 2; ++k) {
      int idx = id * 512 + k * 256 + t;
      float v = (idx < 327680) ? w_in[idx] : w_out[idx - 327680];
      Wb[idx] = (short)f2bf(v);
    }
  } else {  // mean over w -> kcm[b][h][e]
    int bh = id - 768;
    const float4* p = (const float4*)(key_col + (size_t)bh * 24576) + e4 +
                      (size_t)q4 * 24 * 64;
    float4 s = {0.f, 0.f, 0.f, 0.f};
#pragma unroll
    for (int i = 0; i < 24; ++i) {
      float4 v = p[(size_t)i * 64];
      s.x += v.x; s.y += v.y; s.z += v.z; s.w += v.w;
    }
    part[t] = s;
    __syncthreads();
    if (t < 64) {
      float4 a = part[t], c = part[t + 64], d = part[t + 128], e = part[t + 192];
      float4 o;
      o.x = (a.x + c.x + d.x + e.x) * (1.f / 96.f);
      o.y = (a.y + c.y + d.y + e.y) * (1.f / 96.f);
      o.z = (a.z + c.z + d.z + e.z) * (1.f / 96.f);
      o.w = (a.w + c.w + d.w + e.w) * (1.f / 96.f);
      ((float4*)kcm)[(size_t)bh * 64 + t] = o;
    }
  }
}

// ---------------- value projection (r16: 3 blocks/CU) ----------------
__global__ __launch_bounds__(512, 4) void vproj_kernel(
    const float* __restrict__ A, const short* __restrict__ Wb,
    const float* __restrict__ bias, short* __restrict__ vvT) {
  __shared__ float buf[2][16 * 260];   // 33.3 KB
  __shared__ short Ts[8][32 * 36];     // 18.4 KB
  int t = threadIdx.x;
  int wave = t >> 6, lane = t & 63, r = lane & 15, g = lane >> 4;
  int m0g = blockIdx.x * 96;
  int b_ = blockIdx.x / 96;
  int hw00 = (blockIdx.x - b_ * 96) * 96;
  int chbase = wave * 32;

  short8v bf[8][2];
  {
    const short* wbase = Wb + (size_t)(chbase + r) * 256;
#pragma unroll
    for (int ks = 0; ks < 8; ++ks)
#pragma unroll
      for (int nf = 0; nf < 2; ++nf)
        bf[ks][nf] = *(const short8v*)(wbase + nf * 16 * 256 + ks * 32 + g * 8);
  }
#pragma unroll
  for (int ks = 0; ks < 8; ++ks)
#pragma unroll
    for (int nf = 0; nf < 2; ++nf)
      asm volatile("" : "+a"(bf[ks][nf]));
  float bias_v[2];
#pragma unroll
  for (int nf = 0; nf < 2; ++nf) bias_v[nf] = bias[chbase + nf * 16 + r];

#pragma unroll
  for (int q = 0; q < 2; ++q) {
#pragma unroll
    for (int i = 0; i < 2; ++i) {
      int row = wave * 2 + i;
      const float* gp = A + ((size_t)m0g + q * 16 + row) * 256 + lane * 4;
      GLL16(gp, &buf[q][row * 260]);
    }
  }

  int chg = chbase + (lane & 31);
  int half = lane >> 5;
  short* vbase = vvT + (size_t)(b_ * 8 + (chg >> 5)) * 294912 +
                 (size_t)(chg & 31) * 9216 + hw00;
  const short* tsr = &Ts[wave][(lane & 31) * 36];

#pragma unroll
  for (int tt = 0; tt < 6; ++tt) {
    if (tt == 5)                  asm volatile("s_waitcnt vmcnt(0)" ::: "memory");
    else if (tt == 2 || tt == 4)  asm volatile("s_waitcnt vmcnt(4)" ::: "memory");
    else                          asm volatile("s_waitcnt vmcnt(2)" ::: "memory");
    __builtin_amdgcn_s_barrier();

    f32x4 acc[2] = {};
    const float* bp_ = &buf[tt & 1][0];
#pragma unroll
    for (int ks = 0; ks < 8; ++ks) {
      const float* p = bp_ + r * 260 + ks * 32 + g * 8;
      f32x4 lo = *(const f32x4*)p;
      f32x4 hi = *(const f32x4*)(p + 4);
      short8v af = pack8cvt(lo, hi);
      acc[0] = __builtin_amdgcn_mfma_f32_16x16x32_bf16(af, bf[ks][0], acc[0], 0, 0, 0);
      acc[1] = __builtin_amdgcn_mfma_f32_16x16x32_bf16(af, bf[ks][1], acc[1], 0, 0, 0);
    }

#pragma unroll
    for (int nf = 0; nf < 2; ++nf) {
      float bv = bias_v[nf];
      *(short4v*)&Ts[wave][(nf * 16 + r) * 36 + (tt & 1) * 16 + g * 4] =
          pack4cvt(acc[nf][0] + bv, acc[nf][1] + bv, acc[nf][2] + bv, acc[nf][3] + bv);
    }
    asm volatile("" ::: "memory");

    if (tt & 1) {
      short* gdst = vbase + (tt - 1) * 16 + half * 16;
      const short* src = tsr + half * 16;
      *(short8v*)gdst = *(const short8v*)src;
      *(short8v*)(gdst + 8) = *(const short8v*)(src + 8);
      asm volatile("" ::: "memory");
    }

    __builtin_amdgcn_s_barrier();
    if (tt + 2 < 6) {
#pragma unroll
      for (int i = 0; i < 2; ++i) {
        int row = wave * 2 + i;
        const float* gp = A + ((size_t)m0g + (tt + 2) * 16 + row) * 256 + lane * 4;
        GLL16(gp, &buf[tt & 1][row * 260]);
      }
    }
  }
}

// ---------------- gemm512: kproj + qproj in one launch ----------------
__global__ __launch_bounds__(512) void gemm512(
    const float* __restrict__ krm, const float* __restrict__ kcm,
    const float* __restrict__ qrow, const float* __restrict__ qcol,
    const short* __restrict__ Wb, const float* __restrict__ Bv,
    short* __restrict__ krb, short* __restrict__ kcb,
    short* __restrict__ qrb, short* __restrict__ qcb) {
  __shared__ short As[2][32 * 264];
  int id = blockIdx.x;
  const float* A; short* Cb; const short* Wp; const float* bp; int M, m064;
  float scale;
  if (id < 12)      { A = krm;  Cb = krb; Wp = Wb + 131072; bp = Bv + 512; M = 768;  m064 = id * 64;        scale = 1.f; }
  else if (id < 24) { A = kcm;  Cb = kcb; Wp = Wb + 196608; bp = Bv + 768; M = 768;  m064 = (id - 12) * 64; scale = 1.f; }
  else if (id < 62) { A = qrow; Cb = qrb; Wp = Wb;          bp = Bv;       M = 2400; m064 = (id - 24) * 64; scale = SCALE_Q; }
  else              { A = qcol; Cb = qcb; Wp = Wb + 65536;  bp = Bv + 256; M = 2400; m064 = (id - 62) * 64; scale = SCALE_Q; }

  int t = threadIdx.x, sub = t >> 8, u = t & 255;
  int wave = u >> 6, lane = u & 63, r = lane & 15, g = lane >> 4;
  int m0 = m064 + sub * 32;

  {
    int row = u >> 3, c0 = (u & 7) * 32;
    int mrow = m0 + row; if (mrow >= M) mrow = M - 1;
    const float* ap = A + (size_t)mrow * 256 + c0;
    float4 ld[8];
#pragma unroll
    for (int j = 0; j < 8; ++j) ld[j] = *(const float4*)(ap + j * 4);
    short* dst = &As[sub][row * 264 + c0];
#pragma unroll
    for (int j = 0; j < 4; ++j)
      *(short8v*)(dst + j * 8) = pack8(ld[2 * j], ld[2 * j + 1]);
  }
  __syncthreads();

  f32x4 acc[2][4] = {};
  const short* wbase = Wp + (size_t)(wave * 64 + r) * 256;
#pragma unroll
  for (int ks = 0; ks < 8; ++ks) {
    short8v af0 = *(const short8v*)&As[sub][r * 264 + ks * 32 + g * 8];
    short8v af1 = *(const short8v*)&As[sub][(16 + r) * 264 + ks * 32 + g * 8];
    short8v bfr[4];
#pragma unroll
    for (int nf = 0; nf < 4; ++nf)
      bfr[nf] = *(const short8v*)(wbase + nf * 16 * 256 + ks * 32 + g * 8);
#pragma unroll
    for (int nf = 0; nf < 4; ++nf) {
      acc[0][nf] = __builtin_amdgcn_mfma_f32_16x16x32_bf16(af0, bfr[nf], acc[0][nf], 0, 0, 0);
      acc[1][nf] = __builtin_amdgcn_mfma_f32_16x16x32_bf16(af1, bfr[nf], acc[1][nf], 0, 0, 0);
    }
  }

#pragma unroll
  for (int mf = 0; mf < 2; ++mf)
#pragma unroll
    for (int nf = 0; nf < 4; ++nf) {
      int nn = wave * 64 + nf * 16 + r;
      float bval = bp[nn];
#pragma unroll
      for (int i = 0; i < 4; ++i) {
        int m = m0 + mf * 16 + g * 4 + i;
        if (m >= M) continue;
        Cb[(size_t)m * 256 + nn] = (short)f2bf((acc[mf][nf][i] + bval) * scale);
      }
    }
}

// ---------------- out-projection: (p0+p1+p2+p3) @ Wout^T + Bout ----------------
__global__ __launch_bounds__(512) void gemm512_out(
    const float* __restrict__ p0, const float* __restrict__ p1,
    const float* __restrict__ p2, const float* __restrict__ p3,
    const short* __restrict__ Wp, const float* __restrict__ bp,
    float* __restrict__ Cf) {
  __shared__ short As[2][32 * 264];
  const int M = 2400;
  int t = threadIdx.x, sub = t >> 8, u = t & 255;
  int wave = u >> 6, lane = u & 63, r = lane & 15, g = lane >> 4;
  int m0 = blockIdx.x * 64 + sub * 32;

  {
    int row = u >> 3, c0 = (u & 7) * 32;
    int mrow = m0 + row; if (mrow >= M) mrow = M - 1;
    size_t off = (size_t)mrow * 256 + c0;
    float4 ld[8];
#pragma unroll
    for (int j = 0; j < 8; ++j) {
      float4 x = *(const float4*)(p0 + off + j * 4);
      float4 y = *(const float4*)(p1 + off + j * 4);
      float4 z = *(const float4*)(p2 + off + j * 4);
      float4 w = *(const float4*)(p3 + off + j * 4);
      x.x += y.x + z.x + w.x; x.y += y.y + z.y + w.y;
      x.z += y.z + z.z + w.z; x.w += y.w + z.w + w.w;
      ld[j] = x;
    }
    short* dst = &As[sub][row * 264 + c0];
#pragma unroll
    for (int j = 0; j < 4; ++j)
      *(short8v*)(dst + j * 8) = pack8(ld[2 * j], ld[2 * j + 1]);
  }
  __syncthreads();

  f32x4 acc[2][4] = {};
  const short* wbase = Wp + (size_t)(wave * 64 + r) * 256;
#pragma unroll
  for (int ks = 0; ks < 8; ++ks) {
    short8v af0 = *(const short8v*)&As[sub][r * 264 + ks * 32 + g * 8];
    short8v af1 = *(const short8v*)&As[sub][(16 + r) * 264 + ks * 32 + g * 8];
    short8v bfr[4];
#pragma unroll
    for (int nf = 0; nf < 4; ++nf)
      bfr[nf] = *(const short8v*)(wbase + nf * 16 * 256 + ks * 32 + g * 8);
#pragma unroll
    for (int nf = 0; nf < 4; ++nf) {
      acc[0][nf] = __builtin_amdgcn_mfma_f32_16x16x32_bf16(af0, bfr[nf], acc[0][nf], 0, 0, 0);
      acc[1][nf] = __builtin_amdgcn_mfma_f32_16x16x32_bf16(af1, bfr[nf], acc[1][nf], 0, 0, 0);
    }
  }

#pragma unroll
  for (int mf = 0; mf < 2; ++mf)
#pragma unroll
    for (int nf = 0; nf < 4; ++nf) {
      int nn = wave * 64 + nf * 16 + r;
      float bval = bp[nn];
#pragma unroll
      for (int i = 0; i < 4; ++i) {
        int m = m0 + mf * 16 + g * 4 + i;
        if (m >= M) continue;
        int bb = m / 300, ll = m - bb * 300;
        Cf[((size_t)ll * 8 + bb) * 256 + nn] = acc[mf][nf][i] + bval;
      }
    }
}

// ---------------- scores + softmax: MFMA + in-register softmax ----------------
__global__ __launch_bounds__(64) void scores_softmax_v2(
    const short* __restrict__ qrb, const short* __restrict__ qcb,
    const short* __restrict__ krb, const short* __restrict__ kcb,
    short* __restrict__ wrowB, float* __restrict__ wcolT) {
  int lchunk = blockIdx.x, bn = blockIdx.y, kind = blockIdx.z;
  int b = bn >> 3, n = bn & 7;
  int lane = threadIdx.x;
  int r = lane & 15, g = lane >> 4;
  const short* qb = kind ? qcb : qrb;
  const short* kb = kind ? kcb : krb;
  int l0 = lchunk * 80;

  short8v a[5], bfr[6];
#pragma unroll
  for (int lf = 0; lf < 5; ++lf) {
    int l = l0 + lf * 16 + r;
    if (l > 299) l = 299;
    a[lf] = *(const short8v*)(qb + ((size_t)b * 300 + l) * 256 + n * 32 + g * 8);
  }
#pragma unroll
  for (int f = 0; f < 6; ++f)
    bfr[f] = *(const short8v*)(kb + ((size_t)b * 96 + f * 16 + r) * 256 + n * 32 + g * 8);

  f32x4 c[5][6];
#pragma unroll
  for (int lf = 0; lf < 5; ++lf)
#pragma unroll
    for (int f = 0; f < 6; ++f) {
      f32x4 z = {};
      c[lf][f] = __builtin_amdgcn_mfma_f32_16x16x32_bf16(a[lf], bfr[f], z, 0, 0, 0);
    }

#pragma unroll
  for (int lf = 0; lf < 5; ++lf)
#pragma unroll
    for (int i = 0; i < 4; ++i) {
      float m = c[lf][0][i];
#pragma unroll
      for (int f = 1; f < 6; ++f) m = fmaxf(m, c[lf][f][i]);
#pragma unroll
      for (int mask = 1; mask <= 8; mask <<= 1) m = fmaxf(m, __shfl_xor(m, mask, 64));
      float e[6], s = 0.f;
#pragma unroll
      for (int f = 0; f < 6; ++f) { e[f] = __expf(c[lf][f][i] - m); s += e[f]; }
#pragma unroll
      for (int mask = 1; mask <= 8; mask <<= 1) s += __shfl_xor(s, mask, 64);
      float inv = 1.f / s;
#pragma unroll
      for (int f = 0; f < 6; ++f) c[lf][f][i] = e[f] * inv;
    }

  if (kind == 0) {
#pragma unroll
    for (int lf = 0; lf < 5; ++lf)
#pragma unroll
      for (int i = 0; i < 4; ++i) {
        int l = l0 + lf * 16 + g * 4 + i;
        bool ok = (l < 300);
#pragma unroll
        for (int f = 0; f < 6; ++f) {
          float wv = ok ? c[lf][f][i] : 0.f;
          wrowB[((size_t)bn * 320 + l) * 96 + f * 16 + r] = (short)f2bf(wv);
        }
      }
  } else {
#pragma unroll
    for (int lf = 0; lf < 5; ++lf)
#pragma unroll
      for (int f = 0; f < 6; ++f) {
        int l = l0 + lf * 16 + g * 4;
        f32x4 wv = c[lf][f];
#pragma unroll
        for (int i = 0; i < 4; ++i) if (l + i >= 300) wv[i] = 0.f;
        *(f32x4*)(wcolT + ((size_t)bn * 96 + f * 16 + r) * 320 + l) = wv;
      }
  }
}

// ---------------- attention v6: block=(bn, h/4); V LDS-shared, read once ----
// 256 blocks x 512 thr; 8 waves = 2 df x 4 lq(80 l). V h-step (6KB) staged by
// waves 0-5 (3-buffer, counted vmcnt, raw barriers); wcs (30KB) in prologue.
// part[hq][2400][256] fp32 (r16-shape stores), summed in out-proj.
__global__ __launch_bounds__(512, 2) void attn_v6(
    const short* __restrict__ wrowB, const float* __restrict__ wcolT,
    const short* __restrict__ vvT, float* __restrict__ part) {
  __shared__ short Vs[3][384 * 8];   // 3 x 6 KB
  __shared__ float wcs[24 * 320];    // 30 KB
  int bid = blockIdx.x;
  int xcd = bid & 7, idx = bid >> 3;    // idx 0..31
  int hq = idx & 3, bng = idx >> 2;     // all 4 hq-blocks of bn -> same XCD
  int bn = bng * 8 + xcd;
  int hbase = hq * 24;
  int b = bn >> 3, n = bn & 7;
  int t = threadIdx.x, wave = t >> 6, lane = t & 63;
  int df = wave & 1, lq = wave >> 1;
  int l0 = lq * 80;
  int r = lane & 15, g = lane >> 4;

  const short* vbn = vvT + (size_t)bn * 294912;

  // prologue: wcs (1920 granules, fully contiguous) by all 512 threads
  {
    const float* wsrc = wcolT + ((size_t)bn * 96 + hbase) * 320;
    GLL16(wsrc + t * 4, &wcs[t * 4]);
    GLL16(wsrc + (t + 512) * 4, &wcs[(t + 512) * 4]);
    GLL16(wsrc + (t + 1024) * 4, &wcs[(t + 1024) * 4]);
    if (t < 384) GLL16(wsrc + (t + 1536) * 4, &wcs[(t + 1536) * 4]);
  }
  // prologue: Vs[0..2] (h-steps 0..2) by threads t<384 (waves 0-5)
  int sd = t / 12, sq = t - sd * 12;        // granule (d, q)
  int sqs = sq ^ (sd & 3);                  // source pre-permute (involution)
  if (t < 384) {
#pragma unroll
    for (int q3 = 0; q3 < 3; ++q3) {
      const short* src = vbn + (size_t)sd * 9216 + (hbase + q3) * 96 + sqs * 8;
      GLL16(src, &Vs[q3][t * 8]);
    }
  }

  // wr A-frags for this wave's 80 l (rows >=300 zeroed by scores)
  short8v a[5][3];
  const short* wr = wrowB + (size_t)bn * 320 * 96;
#pragma unroll
  for (int lf = 0; lf < 5; ++lf)
#pragma unroll
    for (int ks = 0; ks < 3; ++ks)
      a[lf][ks] = *(const short8v*)(wr + (l0 + lf * 16 + r) * 96 + ks * 32 + g * 8);

  __syncthreads();  // drains all prologue GLLs (per-wave vmcnt(0))

  f32x4 acc[5] = {};
  int d = df * 16 + r;
  int sw = d & 3;

#pragma unroll
  for (int hs = 0; hs < 24; ++hs) {
    if (t < 384) {  // wave-uniform: waves 0-5 entirely t<384
      if (hs <= 21)      asm volatile("s_waitcnt vmcnt(2)" ::: "memory");
      else if (hs == 22) asm volatile("s_waitcnt vmcnt(1)" ::: "memory");
      else               asm volatile("s_waitcnt vmcnt(0)" ::: "memory");
    }
    __builtin_amdgcn_s_barrier();   // Vs[hs%3] certified ready
    asm volatile("" ::: "memory");

    const short* vsb = &Vs[hs % 3][0];
    short8v bfr[3];
#pragma unroll
    for (int ks = 0; ks < 3; ++ks) {
      int q = ks * 4 + g;
      bfr[ks] = *(const short8v*)(vsb + ((size_t)d * 12 + (q ^ sw)) * 8);
    }
    f32x4 R[5] = {};
#pragma unroll
    for (int ks = 0; ks < 3; ++ks)
#pragma unroll
      for (int lf = 0; lf < 5; ++lf)
        R[lf] = __builtin_amdgcn_mfma_f32_16x16x32_bf16(a[lf][ks], bfr[ks], R[lf], 0, 0, 0);
#pragma unroll
    for (int lf = 0; lf < 5; ++lf) {
      f32x4 w = *(const f32x4*)&wcs[hs * 320 + l0 + lf * 16 + g * 4];
      acc[lf] += w * R[lf];
    }

    asm volatile("" ::: "memory");
    __builtin_amdgcn_s_barrier();   // all reads of Vs[hs%3] complete
    if (hs + 3 < 24 && t < 384) {   // refill with h-step hs+3
      const short* src = vbn + (size_t)sd * 9216 + (hbase + hs + 3) * 96 + sqs * 8;
      GLL16(src, &Vs[hs % 3][t * 8]);
    }
  }

  // store fp32 partial, r16 shape: per (lf,i2) 4 x 64B contiguous segments
  float* po = part + (size_t)hq * 614400 + (size_t)b * 300 * 256 + n * 32 + d;
#pragma unroll
  for (int lf = 0; lf < 5; ++lf)
#pragma unroll
    for (int i2 = 0; i2 < 4; ++i2) {
      int l = l0 + lf * 16 + g * 4 + i2;
      if (l < 300) po[(size_t)l * 256] = acc[lf][i2];
    }
}

// ---------------- launch ----------------
extern "C" void kernel_launch(void* const* d_in, const int* in_sizes, int n_in,
                              void* d_out, int out_size, void* d_ws, size_t ws_size,
                              hipStream_t stream) {
  const float* query_row = (const float*)d_in[0];
  const float* query_col = (const float*)d_in[1];
  const float* key_row   = (const float*)d_in[2];
  const float* key_col   = (const float*)d_in[3];
  const float* value     = (const float*)d_in[4];
  const float* W         = (const float*)d_in[5];  // (1280,256)
  const float* Bv        = (const float*)d_in[6];  // (1280,)
  const float* Wout      = (const float*)d_in[7];  // (256,256)
  const float* Bout      = (const float*)d_in[8];  // (256,)

  float* ws = (float*)d_ws;
  float* krm   = ws;                        // 196608 f
  float* kcm   = krm + 196608;              // 196608 f
  float* part  = kcm + 196608;              // 4*614400 = 2457600 f
  float* wcolT = part + 2457600;            // 1966080 f
  short* qrb   = (short*)(wcolT + 1966080); // 614400 s
  short* qcb   = qrb + 614400;              // 614400 s
  short* krb   = qcb + 614400;              // 196608 s
  short* kcb   = krb + 196608;              // 196608 s
  short* wrowB = kcb + 196608;              // 1966080 s
  short* vvT   = wrowB + 1966080;           // 18874368 s
  short* Wb    = vvT + 18874368;            // 393216 s

  means_kernel<<<1536, 256, 0, stream>>>(key_row, key_col, krm, kcm, W, Wout, Wb);
  vproj_kernel<<<768, 512, 0, stream>>>(value, Wb + 262144, Bv + 1024, vvT);
  gemm512<<<100, 512, 0, stream>>>(krm, kcm, query_row, query_col, Wb, Bv,
                                   krb, kcb, qrb, qcb);
  scores_softmax_v2<<<dim3(4, 64, 2), 64, 0, stream>>>(qrb, qcb, krb, kcb, wrowB, wcolT);
  attn_v6<<<256, 512, 0, stream>>>(wrowB, wcolT, vvT, part);
  gemm512_out<<<38, 512, 0, stream>>>(part, part + 614400, part + 1228800,
                                      part + 1843200, Wb + 327680, Bout,
                                      (float*)d_out);
}

// Round 22
// 140.693 us; speedup vs baseline: 2.2206x; 2.2206x over previous
//
#include <hip/hip_runtime.h>
#include <cstdint>

// MultiheadRCDA: N=8, L=300, HH=WW=96, E=256, NH=8, HD=32
// Round 22: revert to r20 config (139.9us measured best) + r21's benign
// homogeneous means+cvt merge. attn v6 abandoned: 3rd confirmation that
// fp32 ~1KB-stride partial stores get ~40x write amplification; V-dedup
// saves nothing (L2/L3 already absorb redundancy, r12: FETCH=25MB).

typedef __attribute__((ext_vector_type(8))) short short8v;  // bf16x8 MFMA frag
typedef __attribute__((ext_vector_type(4))) short short4v;  // 8B packed bf16
typedef __attribute__((ext_vector_type(4))) float f32x4;

#define SCALE_Q 0.17677669529663687f  // 32^-0.5

#define GLL16(gp, lp)                                                   \
  __builtin_amdgcn_global_load_lds(                                     \
      (const __attribute__((address_space(1))) void*)(gp),              \
      (__attribute__((address_space(3))) void*)(lp), 16, 0, 0)

__device__ __forceinline__ unsigned short f2bf(float x) {
  unsigned int u = __builtin_bit_cast(unsigned int, x);
  u += 0x7FFFu + ((u >> 16) & 1u);
  return (unsigned short)(u >> 16);
}

__device__ __forceinline__ unsigned int cvtpk(float a, float b) {
  unsigned int r;
  asm("v_cvt_pk_bf16_f32 %0, %1, %2" : "=v"(r) : "v"(a), "v"(b));
  return r;
}

__device__ __forceinline__ short8v pack8cvt(const f32x4& lo, const f32x4& hi) {
  union { short8v s; unsigned int u[4]; } z;
  z.u[0] = cvtpk(lo[0], lo[1]);
  z.u[1] = cvtpk(lo[2], lo[3]);
  z.u[2] = cvtpk(hi[0], hi[1]);
  z.u[3] = cvtpk(hi[2], hi[3]);
  return z.s;
}

__device__ __forceinline__ short4v pack4cvt(float a, float b, float c, float d) {
  union { short4v s; unsigned int u[2]; } z;
  z.u[0] = cvtpk(a, b);
  z.u[1] = cvtpk(c, d);
  return z.s;
}

__device__ __forceinline__ short8v pack8(const float4& fa, const float4& fb) {
  short8v v;
  v[0] = (short)f2bf(fa.x); v[1] = (short)f2bf(fa.y);
  v[2] = (short)f2bf(fa.z); v[3] = (short)f2bf(fa.w);
  v[4] = (short)f2bf(fb.x); v[5] = (short)f2bf(fb.y);
  v[6] = (short)f2bf(fb.z); v[7] = (short)f2bf(fb.w);
  return v;
}

// ---------------- means (h + w) + weight-convert, one homogeneous kernel ----
__global__ __launch_bounds__(256) void means_kernel(
    const float* __restrict__ key_row, const float* __restrict__ key_col,
    float* __restrict__ krm, float* __restrict__ kcm,
    const float* __restrict__ w_in, const float* __restrict__ w_out,
    short* __restrict__ Wb) {
  __shared__ float4 part[256];
  int id = blockIdx.x;
  int t = threadIdx.x, e4 = t & 63, q4 = t >> 6;
  if (id < 768) {  // mean over h -> krm[b][w][e]
    int bw = id;
    int b = bw / 96, w = bw - b * 96;
    const float4* p = (const float4*)(key_row + ((size_t)b * 9216 + w) * 256) +
                      e4 + (size_t)q4 * 24 * 6144;
    float4 s = {0.f, 0.f, 0.f, 0.f};
#pragma unroll
    for (int i = 0; i < 24; ++i) {
      float4 v = p[(size_t)i * 6144];
      s.x += v.x; s.y += v.y; s.z += v.z; s.w += v.w;
    }
    part[t] = s;
    __syncthreads();
    if (t < 64) {
      float4 a = part[t], c = part[t + 64], d = part[t + 128], e = part[t + 192];
      float4 o;
      o.x = (a.x + c.x + d.x + e.x) * (1.f / 96.f);
      o.y = (a.y + c.y + d.y + e.y) * (1.f / 96.f);
      o.z = (a.z + c.z + d.z + e.z) * (1.f / 96.f);
      o.w = (a.w + c.w + d.w + e.w) * (1.f / 96.f);
      ((float4*)krm)[(size_t)bw * 64 + t] = o;
    }
    // weight-convert tail (768*512 = 393216)
#pragma unroll
    for (int k = 0; k < 2; ++k) {
      int idx = id * 512 + k * 256 + t;
      float v = (idx < 327680) ? w_in[idx] : w_out[idx - 327680];
      Wb[idx] = (short)f2bf(v);
    }
  } else {  // mean over w -> kcm[b][h][e]
    int bh = id - 768;
    const float4* p = (const float4*)(key_col + (size_t)bh * 24576) + e4 +
                      (size_t)q4 * 24 * 64;
    float4 s = {0.f, 0.f, 0.f, 0.f};
#pragma unroll
    for (int i = 0; i < 24; ++i) {
      float4 v = p[(size_t)i * 64];
      s.x += v.x; s.y += v.y; s.z += v.z; s.w += v.w;
    }
    part[t] = s;
    __syncthreads();
    if (t < 64) {
      float4 a = part[t], c = part[t + 64], d = part[t + 128], e = part[t + 192];
      float4 o;
      o.x = (a.x + c.x + d.x + e.x) * (1.f / 96.f);
      o.y = (a.y + c.y + d.y + e.y) * (1.f / 96.f);
      o.z = (a.z + c.z + d.z + e.z) * (1.f / 96.f);
      o.w = (a.w + c.w + d.w + e.w) * (1.f / 96.f);
      ((float4*)kcm)[(size_t)bh * 64 + t] = o;
    }
  }
}

// ---------------- value projection (r16: 3 blocks/CU) ----------------
__global__ __launch_bounds__(512, 4) void vproj_kernel(
    const float* __restrict__ A, const short* __restrict__ Wb,
    const float* __restrict__ bias, short* __restrict__ vvT) {
  __shared__ float buf[2][16 * 260];   // 33.3 KB
  __shared__ short Ts[8][32 * 36];     // 18.4 KB
  int t = threadIdx.x;
  int wave = t >> 6, lane = t & 63, r = lane & 15, g = lane >> 4;
  int m0g = blockIdx.x * 96;
  int b_ = blockIdx.x / 96;
  int hw00 = (blockIdx.x - b_ * 96) * 96;
  int chbase = wave * 32;

  short8v bf[8][2];
  {
    const short* wbase = Wb + (size_t)(chbase + r) * 256;
#pragma unroll
    for (int ks = 0; ks < 8; ++ks)
#pragma unroll
      for (int nf = 0; nf < 2; ++nf)
        bf[ks][nf] = *(const short8v*)(wbase + nf * 16 * 256 + ks * 32 + g * 8);
  }
#pragma unroll
  for (int ks = 0; ks < 8; ++ks)
#pragma unroll
    for (int nf = 0; nf < 2; ++nf)
      asm volatile("" : "+a"(bf[ks][nf]));
  float bias_v[2];
#pragma unroll
  for (int nf = 0; nf < 2; ++nf) bias_v[nf] = bias[chbase + nf * 16 + r];

#pragma unroll
  for (int q = 0; q < 2; ++q) {
#pragma unroll
    for (int i = 0; i < 2; ++i) {
      int row = wave * 2 + i;
      const float* gp = A + ((size_t)m0g + q * 16 + row) * 256 + lane * 4;
      GLL16(gp, &buf[q][row * 260]);
    }
  }

  int chg = chbase + (lane & 31);
  int half = lane >> 5;
  short* vbase = vvT + (size_t)(b_ * 8 + (chg >> 5)) * 294912 +
                 (size_t)(chg & 31) * 9216 + hw00;
  const short* tsr = &Ts[wave][(lane & 31) * 36];

#pragma unroll
  for (int tt = 0; tt < 6; ++tt) {
    if (tt == 5)                  asm volatile("s_waitcnt vmcnt(0)" ::: "memory");
    else if (tt == 2 || tt == 4)  asm volatile("s_waitcnt vmcnt(4)" ::: "memory");
    else                          asm volatile("s_waitcnt vmcnt(2)" ::: "memory");
    __builtin_amdgcn_s_barrier();

    f32x4 acc[2] = {};
    const float* bp_ = &buf[tt & 1][0];
#pragma unroll
    for (int ks = 0; ks < 8; ++ks) {
      const float* p = bp_ + r * 260 + ks * 32 + g * 8;
      f32x4 lo = *(const f32x4*)p;
      f32x4 hi = *(const f32x4*)(p + 4);
      short8v af = pack8cvt(lo, hi);
      acc[0] = __builtin_amdgcn_mfma_f32_16x16x32_bf16(af, bf[ks][0], acc[0], 0, 0, 0);
      acc[1] = __builtin_amdgcn_mfma_f32_16x16x32_bf16(af, bf[ks][1], acc[1], 0, 0, 0);
    }

#pragma unroll
    for (int nf = 0; nf < 2; ++nf) {
      float bv = bias_v[nf];
      *(short4v*)&Ts[wave][(nf * 16 + r) * 36 + (tt & 1) * 16 + g * 4] =
          pack4cvt(acc[nf][0] + bv, acc[nf][1] + bv, acc[nf][2] + bv, acc[nf][3] + bv);
    }
    asm volatile("" ::: "memory");

    if (tt & 1) {
      short* gdst = vbase + (tt - 1) * 16 + half * 16;
      const short* src = tsr + half * 16;
      *(short8v*)gdst = *(const short8v*)src;
      *(short8v*)(gdst + 8) = *(const short8v*)(src + 8);
      asm volatile("" ::: "memory");
    }

    __builtin_amdgcn_s_barrier();
    if (tt + 2 < 6) {
#pragma unroll
      for (int i = 0; i < 2; ++i) {
        int row = wave * 2 + i;
        const float* gp = A + ((size_t)m0g + (tt + 2) * 16 + row) * 256 + lane * 4;
        GLL16(gp, &buf[tt & 1][row * 260]);
      }
    }
  }
}

// ---------------- gemm512: kproj + qproj in one launch ----------------
__global__ __launch_bounds__(512) void gemm512(
    const float* __restrict__ krm, const float* __restrict__ kcm,
    const float* __restrict__ qrow, const float* __restrict__ qcol,
    const short* __restrict__ Wb, const float* __restrict__ Bv,
    short* __restrict__ krb, short* __restrict__ kcb,
    short* __restrict__ qrb, short* __restrict__ qcb) {
  __shared__ short As[2][32 * 264];
  int id = blockIdx.x;
  const float* A; short* Cb; const short* Wp; const float* bp; int M, m064;
  float scale;
  if (id < 12)      { A = krm;  Cb = krb; Wp = Wb + 131072; bp = Bv + 512; M = 768;  m064 = id * 64;        scale = 1.f; }
  else if (id < 24) { A = kcm;  Cb = kcb; Wp = Wb + 196608; bp = Bv + 768; M = 768;  m064 = (id - 12) * 64; scale = 1.f; }
  else if (id < 62) { A = qrow; Cb = qrb; Wp = Wb;          bp = Bv;       M = 2400; m064 = (id - 24) * 64; scale = SCALE_Q; }
  else              { A = qcol; Cb = qcb; Wp = Wb + 65536;  bp = Bv + 256; M = 2400; m064 = (id - 62) * 64; scale = SCALE_Q; }

  int t = threadIdx.x, sub = t >> 8, u = t & 255;
  int wave = u >> 6, lane = u & 63, r = lane & 15, g = lane >> 4;
  int m0 = m064 + sub * 32;

  {
    int row = u >> 3, c0 = (u & 7) * 32;
    int mrow = m0 + row; if (mrow >= M) mrow = M - 1;
    const float* ap = A + (size_t)mrow * 256 + c0;
    float4 ld[8];
#pragma unroll
    for (int j = 0; j < 8; ++j) ld[j] = *(const float4*)(ap + j * 4);
    short* dst = &As[sub][row * 264 + c0];
#pragma unroll
    for (int j = 0; j < 4; ++j)
      *(short8v*)(dst + j * 8) = pack8(ld[2 * j], ld[2 * j + 1]);
  }
  __syncthreads();

  f32x4 acc[2][4] = {};
  const short* wbase = Wp + (size_t)(wave * 64 + r) * 256;
#pragma unroll
  for (int ks = 0; ks < 8; ++ks) {
    short8v af0 = *(const short8v*)&As[sub][r * 264 + ks * 32 + g * 8];
    short8v af1 = *(const short8v*)&As[sub][(16 + r) * 264 + ks * 32 + g * 8];
    short8v bfr[4];
#pragma unroll
    for (int nf = 0; nf < 4; ++nf)
      bfr[nf] = *(const short8v*)(wbase + nf * 16 * 256 + ks * 32 + g * 8);
#pragma unroll
    for (int nf = 0; nf < 4; ++nf) {
      acc[0][nf] = __builtin_amdgcn_mfma_f32_16x16x32_bf16(af0, bfr[nf], acc[0][nf], 0, 0, 0);
      acc[1][nf] = __builtin_amdgcn_mfma_f32_16x16x32_bf16(af1, bfr[nf], acc[1][nf], 0, 0, 0);
    }
  }

#pragma unroll
  for (int mf = 0; mf < 2; ++mf)
#pragma unroll
    for (int nf = 0; nf < 4; ++nf) {
      int nn = wave * 64 + nf * 16 + r;
      float bval = bp[nn];
#pragma unroll
      for (int i = 0; i < 4; ++i) {
        int m = m0 + mf * 16 + g * 4 + i;
        if (m >= M) continue;
        Cb[(size_t)m * 256 + nn] = (short)f2bf((acc[mf][nf][i] + bval) * scale);
      }
    }
}

// ---------------- out-projection: (part0+part1) @ Wout^T + Bout ----------------
__global__ __launch_bounds__(512) void gemm512_out(
    const float* __restrict__ p0, const float* __restrict__ p1,
    const short* __restrict__ Wp, const float* __restrict__ bp,
    float* __restrict__ Cf) {
  __shared__ short As[2][32 * 264];
  const int M = 2400;
  int t = threadIdx.x, sub = t >> 8, u = t & 255;
  int wave = u >> 6, lane = u & 63, r = lane & 15, g = lane >> 4;
  int m0 = blockIdx.x * 64 + sub * 32;

  {
    int row = u >> 3, c0 = (u & 7) * 32;
    int mrow = m0 + row; if (mrow >= M) mrow = M - 1;
    size_t off = (size_t)mrow * 256 + c0;
    float4 ld[8];
#pragma unroll
    for (int j = 0; j < 8; ++j) {
      float4 x = *(const float4*)(p0 + off + j * 4);
      float4 y = *(const float4*)(p1 + off + j * 4);
      x.x += y.x; x.y += y.y; x.z += y.z; x.w += y.w;
      ld[j] = x;
    }
    short* dst = &As[sub][row * 264 + c0];
#pragma unroll
    for (int j = 0; j < 4; ++j)
      *(short8v*)(dst + j * 8) = pack8(ld[2 * j], ld[2 * j + 1]);
  }
  __syncthreads();

  f32x4 acc[2][4] = {};
  const short* wbase = Wp + (size_t)(wave * 64 + r) * 256;
#pragma unroll
  for (int ks = 0; ks < 8; ++ks) {
    short8v af0 = *(const short8v*)&As[sub][r * 264 + ks * 32 + g * 8];
    short8v af1 = *(const short8v*)&As[sub][(16 + r) * 264 + ks * 32 + g * 8];
    short8v bfr[4];
#pragma unroll
    for (int nf = 0; nf < 4; ++nf)
      bfr[nf] = *(const short8v*)(wbase + nf * 16 * 256 + ks * 32 + g * 8);
#pragma unroll
    for (int nf = 0; nf < 4; ++nf) {
      acc[0][nf] = __builtin_amdgcn_mfma_f32_16x16x32_bf16(af0, bfr[nf], acc[0][nf], 0, 0, 0);
      acc[1][nf] = __builtin_amdgcn_mfma_f32_16x16x32_bf16(af1, bfr[nf], acc[1][nf], 0, 0, 0);
    }
  }

#pragma unroll
  for (int mf = 0; mf < 2; ++mf)
#pragma unroll
    for (int nf = 0; nf < 4; ++nf) {
      int nn = wave * 64 + nf * 16 + r;
      float bval = bp[nn];
#pragma unroll
      for (int i = 0; i < 4; ++i) {
        int m = m0 + mf * 16 + g * 4 + i;
        if (m >= M) continue;
        int bb = m / 300, ll = m - bb * 300;
        Cf[((size_t)ll * 8 + bb) * 256 + nn] = acc[mf][nf][i] + bval;
      }
    }
}

// ---------------- scores + softmax: MFMA + in-register softmax ----------------
__global__ __launch_bounds__(64) void scores_softmax_v2(
    const short* __restrict__ qrb, const short* __restrict__ qcb,
    const short* __restrict__ krb, const short* __restrict__ kcb,
    short* __restrict__ wrowB, float* __restrict__ wcolT) {
  int lchunk = blockIdx.x, bn = blockIdx.y, kind = blockIdx.z;
  int b = bn >> 3, n = bn & 7;
  int lane = threadIdx.x;
  int r = lane & 15, g = lane >> 4;
  const short* qb = kind ? qcb : qrb;
  const short* kb = kind ? kcb : krb;
  int l0 = lchunk * 80;

  short8v a[5], bfr[6];
#pragma unroll
  for (int lf = 0; lf < 5; ++lf) {
    int l = l0 + lf * 16 + r;
    if (l > 299) l = 299;
    a[lf] = *(const short8v*)(qb + ((size_t)b * 300 + l) * 256 + n * 32 + g * 8);
  }
#pragma unroll
  for (int f = 0; f < 6; ++f)
    bfr[f] = *(const short8v*)(kb + ((size_t)b * 96 + f * 16 + r) * 256 + n * 32 + g * 8);

  f32x4 c[5][6];
#pragma unroll
  for (int lf = 0; lf < 5; ++lf)
#pragma unroll
    for (int f = 0; f < 6; ++f) {
      f32x4 z = {};
      c[lf][f] = __builtin_amdgcn_mfma_f32_16x16x32_bf16(a[lf], bfr[f], z, 0, 0, 0);
    }

#pragma unroll
  for (int lf = 0; lf < 5; ++lf)
#pragma unroll
    for (int i = 0; i < 4; ++i) {
      float m = c[lf][0][i];
#pragma unroll
      for (int f = 1; f < 6; ++f) m = fmaxf(m, c[lf][f][i]);
#pragma unroll
      for (int mask = 1; mask <= 8; mask <<= 1) m = fmaxf(m, __shfl_xor(m, mask, 64));
      float e[6], s = 0.f;
#pragma unroll
      for (int f = 0; f < 6; ++f) { e[f] = __expf(c[lf][f][i] - m); s += e[f]; }
#pragma unroll
      for (int mask = 1; mask <= 8; mask <<= 1) s += __shfl_xor(s, mask, 64);
      float inv = 1.f / s;
#pragma unroll
      for (int f = 0; f < 6; ++f) c[lf][f][i] = e[f] * inv;
    }

  if (kind == 0) {
#pragma unroll
    for (int lf = 0; lf < 5; ++lf)
#pragma unroll
      for (int i = 0; i < 4; ++i) {
        int l = l0 + lf * 16 + g * 4 + i;
        bool ok = (l < 300);
#pragma unroll
        for (int f = 0; f < 6; ++f) {
          float wv = ok ? c[lf][f][i] : 0.f;
          wrowB[((size_t)bn * 320 + l) * 96 + f * 16 + r] = (short)f2bf(wv);
        }
      }
  } else {
#pragma unroll
    for (int lf = 0; lf < 5; ++lf)
#pragma unroll
      for (int f = 0; f < 6; ++f) {
        int l = l0 + lf * 16 + g * 4;
        f32x4 wv = c[lf][f];
#pragma unroll
        for (int i = 0; i < 4; ++i) if (l + i >= 300) wv[i] = 0.f;
        *(f32x4*)(wcolT + ((size_t)bn * 96 + f * 16 + r) * 320 + l) = wv;
      }
  }
}

// ---------------- attention v5 (r20): r16 h-split + wcolT LDS-staged ----------
__global__ __launch_bounds__(512, 2) void attn_kernel(
    const short* __restrict__ wrowB, const float* __restrict__ wcolT,
    const short* __restrict__ vvT, float* __restrict__ part0,
    float* __restrict__ part1) {
  __shared__ f32x4 cmb[3][2][4][64];  // 24.6 KB
  __shared__ float wcs[48][64];       // 12.3 KB
  int i = blockIdx.x;
  int xcd = i & 7, j = i >> 3;          // j 0..79
  int grp = j / 10, rem = j - grp * 10;
  int bn = grp * 8 + xcd;               // all 10 blocks of a bn -> same XCD
  int lh = rem >> 1, hh2 = rem & 1;
  int b = bn >> 3, n = bn & 7;
  int t = threadIdx.x, wave = t >> 6, lane = t & 63;
  int df = wave & 1, hq = wave >> 1;    // hq 0..3, 12 h each
  int lbase = lh * 64;
  int r = lane & 15, g = lane >> 4;
  int hbase = hh2 * 48 + hq * 12;

  // stage wc slice (48 h x 64 l) once per block
  {
    const float* wsrc = wcolT + ((size_t)bn * 96 + hh2 * 48) * 320 + lbase;
#pragma unroll
    for (int k = 0; k < 2; ++k) {
      int u = t + k * 512;
      if (u < 768) {
        int row = u >> 4, cb = (u & 15) * 4;
        *(f32x4*)&wcs[row][cb] = *(const f32x4*)(wsrc + row * 320 + cb);
      }
    }
  }

  short8v a[4][3];
  const short* wr = wrowB + (size_t)bn * 320 * 96;
#pragma unroll
  for (int lf = 0; lf < 4; ++lf)
#pragma unroll
    for (int ks = 0; ks < 3; ++ks)
      a[lf][ks] = *(const short8v*)(wr + (lbase + lf * 16 + r) * 96 + ks * 32 + g * 8);

  const short* vb = vvT + (size_t)bn * 294912 + (size_t)(df * 16 + r) * 9216 + hbase * 96;
  __syncthreads();  // wcs ready

  f32x4 acc[4] = {};
  short8v b0[3], b1[3];
  int hl = hq * 12;
#pragma unroll
  for (int ks = 0; ks < 3; ++ks) b0[ks] = *(const short8v*)(vb + ks * 32 + g * 8);

#pragma unroll
  for (int h2 = 0; h2 < 6; ++h2) {
    int h = h2 * 2;
#pragma unroll
    for (int ks = 0; ks < 3; ++ks) b1[ks] = *(const short8v*)(vb + (h + 1) * 96 + ks * 32 + g * 8);
    {
      f32x4 R[4] = {};
#pragma unroll
      for (int ks = 0; ks < 3; ++ks)
#pragma unroll
        for (int lf = 0; lf < 4; ++lf)
          R[lf] = __builtin_amdgcn_mfma_f32_16x16x32_bf16(a[lf][ks], b0[ks], R[lf], 0, 0, 0);
#pragma unroll
      for (int lf = 0; lf < 4; ++lf) {
        f32x4 w = *(const f32x4*)&wcs[hl + h][lf * 16 + g * 4];
        acc[lf] += w * R[lf];
      }
    }
    if (h2 < 5) {
#pragma unroll
      for (int ks = 0; ks < 3; ++ks) b0[ks] = *(const short8v*)(vb + (h + 2) * 96 + ks * 32 + g * 8);
    }
    {
      f32x4 R[4] = {};
#pragma unroll
      for (int ks = 0; ks < 3; ++ks)
#pragma unroll
        for (int lf = 0; lf < 4; ++lf)
          R[lf] = __builtin_amdgcn_mfma_f32_16x16x32_bf16(a[lf][ks], b1[ks], R[lf], 0, 0, 0);
#pragma unroll
      for (int lf = 0; lf < 4; ++lf) {
        f32x4 w = *(const f32x4*)&wcs[hl + h + 1][lf * 16 + g * 4];
        acc[lf] += w * R[lf];
      }
    }
  }

  if (hq > 0) {
#pragma unroll
    for (int lf = 0; lf < 4; ++lf) cmb[hq - 1][df][lf][lane] = acc[lf];
  }
  __syncthreads();
  if (hq == 0) {
    float* po = hh2 ? part1 : part0;
#pragma unroll
    for (int lf = 0; lf < 4; ++lf) {
      f32x4 o = acc[lf];
#pragma unroll
      for (int q = 0; q < 3; ++q) o += cmb[q][df][lf][lane];
#pragma unroll
      for (int i2 = 0; i2 < 4; ++i2) {
        int l = lbase + lf * 16 + g * 4 + i2;
        if (l < 300)
          po[((size_t)b * 300 + l) * 256 + n * 32 + df * 16 + r] = o[i2];
      }
    }
  }
}

// ---------------- launch ----------------
extern "C" void kernel_launch(void* const* d_in, const int* in_sizes, int n_in,
                              void* d_out, int out_size, void* d_ws, size_t ws_size,
                              hipStream_t stream) {
  const float* query_row = (const float*)d_in[0];
  const float* query_col = (const float*)d_in[1];
  const float* key_row   = (const float*)d_in[2];
  const float* key_col   = (const float*)d_in[3];
  const float* value     = (const float*)d_in[4];
  const float* W         = (const float*)d_in[5];  // (1280,256)
  const float* Bv        = (const float*)d_in[6];  // (1280,)
  const float* Wout      = (const float*)d_in[7];  // (256,256)
  const float* Bout      = (const float*)d_in[8];  // (256,)

  float* ws = (float*)d_ws;
  float* krm   = ws;                        // 196608 f
  float* kcm   = krm + 196608;              // 196608 f
  float* part0 = kcm + 196608;              // 614400 f
  float* part1 = part0 + 614400;            // 614400 f
  float* wcolT = part1 + 614400;            // 1966080 f
  short* qrb   = (short*)(wcolT + 1966080); // 614400 s
  short* qcb   = qrb + 614400;              // 614400 s
  short* krb   = qcb + 614400;              // 196608 s
  short* kcb   = krb + 196608;              // 196608 s
  short* wrowB = kcb + 196608;              // 1966080 s
  short* vvT   = wrowB + 1966080;           // 18874368 s
  short* Wb    = vvT + 18874368;            // 393216 s

  means_kernel<<<1536, 256, 0, stream>>>(key_row, key_col, krm, kcm, W, Wout, Wb);
  vproj_kernel<<<768, 512, 0, stream>>>(value, Wb + 262144, Bv + 1024, vvT);
  gemm512<<<100, 512, 0, stream>>>(krm, kcm, query_row, query_col, Wb, Bv,
                                   krb, kcb, qrb, qcb);
  scores_softmax_v2<<<dim3(4, 64, 2), 64, 0, stream>>>(qrb, qcb, krb, kcb, wrowB, wcolT);
  attn_kernel<<<640, 512, 0, stream>>>(wrowB, wcolT, vvT, part0, part1);
  gemm512_out<<<38, 512, 0, stream>>>(part0, part1, Wb + 327680, Bout, (float*)d_out);
}

// Round 23
// 140.573 us; speedup vs baseline: 2.2225x; 1.0009x over previous
//
#include <hip/hip_runtime.h>
#include <cstdint>

// MultiheadRCDA: N=8, L=300, HH=WW=96, E=256, NH=8, HD=8? no: NH=8, HD=32
// Round 23: means v4 — DRAM-burst contiguity. mean_h: block=(b,4w), 4 waves
// on adjacent w -> 4KB contiguous per h-step, register-resident. mean_w:
// linear 4KB marching through each (b,h) plane. cvt tail vectorized.
// Everything else identical to r22 (140.7us).

typedef __attribute__((ext_vector_type(8))) short short8v;  // bf16x8 MFMA frag
typedef __attribute__((ext_vector_type(4))) short short4v;  // 8B packed bf16
typedef __attribute__((ext_vector_type(4))) float f32x4;

#define SCALE_Q 0.17677669529663687f  // 32^-0.5

#define GLL16(gp, lp)                                                   \
  __builtin_amdgcn_global_load_lds(                                     \
      (const __attribute__((address_space(1))) void*)(gp),              \
      (__attribute__((address_space(3))) void*)(lp), 16, 0, 0)

__device__ __forceinline__ unsigned short f2bf(float x) {
  unsigned int u = __builtin_bit_cast(unsigned int, x);
  u += 0x7FFFu + ((u >> 16) & 1u);
  return (unsigned short)(u >> 16);
}

__device__ __forceinline__ unsigned int cvtpk(float a, float b) {
  unsigned int r;
  asm("v_cvt_pk_bf16_f32 %0, %1, %2" : "=v"(r) : "v"(a), "v"(b));
  return r;
}

__device__ __forceinline__ short8v pack8cvt(const f32x4& lo, const f32x4& hi) {
  union { short8v s; unsigned int u[4]; } z;
  z.u[0] = cvtpk(lo[0], lo[1]);
  z.u[1] = cvtpk(lo[2], lo[3]);
  z.u[2] = cvtpk(hi[0], hi[1]);
  z.u[3] = cvtpk(hi[2], hi[3]);
  return z.s;
}

__device__ __forceinline__ short4v pack4cvt(float a, float b, float c, float d) {
  union { short4v s; unsigned int u[2]; } z;
  z.u[0] = cvtpk(a, b);
  z.u[1] = cvtpk(c, d);
  return z.s;
}

__device__ __forceinline__ short8v pack8(const float4& fa, const float4& fb) {
  short8v v;
  v[0] = (short)f2bf(fa.x); v[1] = (short)f2bf(fa.y);
  v[2] = (short)f2bf(fa.z); v[3] = (short)f2bf(fa.w);
  v[4] = (short)f2bf(fb.x); v[5] = (short)f2bf(fb.y);
  v[6] = (short)f2bf(fb.z); v[7] = (short)f2bf(fb.w);
  return v;
}

// ---------------- means v4 (burst-contiguous) + weight-convert ----------------
// ids 0..191: mean_h, block=(b, 4w), 4 waves = 4 adjacent w, 4KB/h-step.
// ids 192..959: mean_w, block=(b,h), linear 4KB marching through the plane.
__global__ __launch_bounds__(256) void means_kernel(
    const float* __restrict__ key_row, const float* __restrict__ key_col,
    float* __restrict__ krm, float* __restrict__ kcm,
    const float* __restrict__ w_in, const float* __restrict__ w_out,
    short* __restrict__ Wb) {
  __shared__ f32x4 part[256];
  int id = blockIdx.x;
  int t = threadIdx.x;
  if (id < 192) {
    // mean over h -> krm[b][w][e]; register-resident, 4KB contiguous bursts
    int b = id / 24, wq = id - b * 24;
    int wv = t >> 6, e4 = t & 63;
    int w = wq * 4 + wv;
    const f32x4* p = (const f32x4*)key_row + ((size_t)b * 96 * 96 + w) * 64 + e4;
    f32x4 a0 = {0.f, 0.f, 0.f, 0.f}, a1 = a0, a2 = a0, a3 = a0;
#pragma unroll
    for (int i = 0; i < 12; ++i) {
      f32x4 v0 = p[(size_t)(i * 8 + 0) * 6144];
      f32x4 v1 = p[(size_t)(i * 8 + 1) * 6144];
      f32x4 v2 = p[(size_t)(i * 8 + 2) * 6144];
      f32x4 v3 = p[(size_t)(i * 8 + 3) * 6144];
      f32x4 v4 = p[(size_t)(i * 8 + 4) * 6144];
      f32x4 v5 = p[(size_t)(i * 8 + 5) * 6144];
      f32x4 v6 = p[(size_t)(i * 8 + 6) * 6144];
      f32x4 v7 = p[(size_t)(i * 8 + 7) * 6144];
      a0 += v0; a1 += v1; a2 += v2; a3 += v3;
      a0 += v4; a1 += v5; a2 += v6; a3 += v7;
    }
    f32x4 o = (a0 + a1 + a2 + a3) * (1.f / 96.f);
    *((f32x4*)krm + ((size_t)b * 96 + w) * 64 + e4) = o;
    // vectorized weight-convert tail: 192 blocks x 2048 elems = 393216
    {
      int idx8 = id * 2048 + t * 8;
      f32x4 lo, hi;
      if (idx8 < 327680) {
        lo = *(const f32x4*)(w_in + idx8);
        hi = *(const f32x4*)(w_in + idx8 + 4);
      } else {
        lo = *(const f32x4*)(w_out + idx8 - 327680);
        hi = *(const f32x4*)(w_out + idx8 - 327680 + 4);
      }
      *(short8v*)(Wb + idx8) = pack8cvt(lo, hi);
    }
  } else {
    // mean over w -> kcm[b][h][e]; linear march through contiguous plane
    int bh = id - 192;
    const f32x4* p = (const f32x4*)(key_col + (size_t)bh * 24576);
    f32x4 a0 = {0.f, 0.f, 0.f, 0.f}, a1 = a0, a2 = a0, a3 = a0;
#pragma unroll
    for (int i = 0; i < 6; ++i) {
      f32x4 v0 = p[(i * 4 + 0) * 256 + t];
      f32x4 v1 = p[(i * 4 + 1) * 256 + t];
      f32x4 v2 = p[(i * 4 + 2) * 256 + t];
      f32x4 v3 = p[(i * 4 + 3) * 256 + t];
      a0 += v0; a1 += v1; a2 += v2; a3 += v3;
    }
    part[t] = a0 + a1 + a2 + a3;
    __syncthreads();
    if (t < 64) {
      f32x4 o = (part[t] + part[t + 64] + part[t + 128] + part[t + 192]) *
                (1.f / 96.f);
      *((f32x4*)kcm + (size_t)bh * 64 + t) = o;
    }
  }
}

// ---------------- value projection (r16: 3 blocks/CU) ----------------
__global__ __launch_bounds__(512, 4) void vproj_kernel(
    const float* __restrict__ A, const short* __restrict__ Wb,
    const float* __restrict__ bias, short* __restrict__ vvT) {
  __shared__ float buf[2][16 * 260];   // 33.3 KB
  __shared__ short Ts[8][32 * 36];     // 18.4 KB
  int t = threadIdx.x;
  int wave = t >> 6, lane = t & 63, r = lane & 15, g = lane >> 4;
  int m0g = blockIdx.x * 96;
  int b_ = blockIdx.x / 96;
  int hw00 = (blockIdx.x - b_ * 96) * 96;
  int chbase = wave * 32;

  short8v bf[8][2];
  {
    const short* wbase = Wb + (size_t)(chbase + r) * 256;
#pragma unroll
    for (int ks = 0; ks < 8; ++ks)
#pragma unroll
      for (int nf = 0; nf < 2; ++nf)
        bf[ks][nf] = *(const short8v*)(wbase + nf * 16 * 256 + ks * 32 + g * 8);
  }
#pragma unroll
  for (int ks = 0; ks < 8; ++ks)
#pragma unroll
    for (int nf = 0; nf < 2; ++nf)
      asm volatile("" : "+a"(bf[ks][nf]));
  float bias_v[2];
#pragma unroll
  for (int nf = 0; nf < 2; ++nf) bias_v[nf] = bias[chbase + nf * 16 + r];

#pragma unroll
  for (int q = 0; q < 2; ++q) {
#pragma unroll
    for (int i = 0; i < 2; ++i) {
      int row = wave * 2 + i;
      const float* gp = A + ((size_t)m0g + q * 16 + row) * 256 + lane * 4;
      GLL16(gp, &buf[q][row * 260]);
    }
  }

  int chg = chbase + (lane & 31);
  int half = lane >> 5;
  short* vbase = vvT + (size_t)(b_ * 8 + (chg >> 5)) * 294912 +
                 (size_t)(chg & 31) * 9216 + hw00;
  const short* tsr = &Ts[wave][(lane & 31) * 36];

#pragma unroll
  for (int tt = 0; tt < 6; ++tt) {
    if (tt == 5)                  asm volatile("s_waitcnt vmcnt(0)" ::: "memory");
    else if (tt == 2 || tt == 4)  asm volatile("s_waitcnt vmcnt(4)" ::: "memory");
    else                          asm volatile("s_waitcnt vmcnt(2)" ::: "memory");
    __builtin_amdgcn_s_barrier();

    f32x4 acc[2] = {};
    const float* bp_ = &buf[tt & 1][0];
#pragma unroll
    for (int ks = 0; ks < 8; ++ks) {
      const float* p = bp_ + r * 260 + ks * 32 + g * 8;
      f32x4 lo = *(const f32x4*)p;
      f32x4 hi = *(const f32x4*)(p + 4);
      short8v af = pack8cvt(lo, hi);
      acc[0] = __builtin_amdgcn_mfma_f32_16x16x32_bf16(af, bf[ks][0], acc[0], 0, 0, 0);
      acc[1] = __builtin_amdgcn_mfma_f32_16x16x32_bf16(af, bf[ks][1], acc[1], 0, 0, 0);
    }

#pragma unroll
    for (int nf = 0; nf < 2; ++nf) {
      float bv = bias_v[nf];
      *(short4v*)&Ts[wave][(nf * 16 + r) * 36 + (tt & 1) * 16 + g * 4] =
          pack4cvt(acc[nf][0] + bv, acc[nf][1] + bv, acc[nf][2] + bv, acc[nf][3] + bv);
    }
    asm volatile("" ::: "memory");

    if (tt & 1) {
      short* gdst = vbase + (tt - 1) * 16 + half * 16;
      const short* src = tsr + half * 16;
      *(short8v*)gdst = *(const short8v*)src;
      *(short8v*)(gdst + 8) = *(const short8v*)(src + 8);
      asm volatile("" ::: "memory");
    }

    __builtin_amdgcn_s_barrier();
    if (tt + 2 < 6) {
#pragma unroll
      for (int i = 0; i < 2; ++i) {
        int row = wave * 2 + i;
        const float* gp = A + ((size_t)m0g + (tt + 2) * 16 + row) * 256 + lane * 4;
        GLL16(gp, &buf[tt & 1][row * 260]);
      }
    }
  }
}

// ---------------- gemm512: kproj + qproj in one launch ----------------
__global__ __launch_bounds__(512) void gemm512(
    const float* __restrict__ krm, const float* __restrict__ kcm,
    const float* __restrict__ qrow, const float* __restrict__ qcol,
    const short* __restrict__ Wb, const float* __restrict__ Bv,
    short* __restrict__ krb, short* __restrict__ kcb,
    short* __restrict__ qrb, short* __restrict__ qcb) {
  __shared__ short As[2][32 * 264];
  int id = blockIdx.x;
  const float* A; short* Cb; const short* Wp; const float* bp; int M, m064;
  float scale;
  if (id < 12)      { A = krm;  Cb = krb; Wp = Wb + 131072; bp = Bv + 512; M = 768;  m064 = id * 64;        scale = 1.f; }
  else if (id < 24) { A = kcm;  Cb = kcb; Wp = Wb + 196608; bp = Bv + 768; M = 768;  m064 = (id - 12) * 64; scale = 1.f; }
  else if (id < 62) { A = qrow; Cb = qrb; Wp = Wb;          bp = Bv;       M = 2400; m064 = (id - 24) * 64; scale = SCALE_Q; }
  else              { A = qcol; Cb = qcb; Wp = Wb + 65536;  bp = Bv + 256; M = 2400; m064 = (id - 62) * 64; scale = SCALE_Q; }

  int t = threadIdx.x, sub = t >> 8, u = t & 255;
  int wave = u >> 6, lane = u & 63, r = lane & 15, g = lane >> 4;
  int m0 = m064 + sub * 32;

  {
    int row = u >> 3, c0 = (u & 7) * 32;
    int mrow = m0 + row; if (mrow >= M) mrow = M - 1;
    const float* ap = A + (size_t)mrow * 256 + c0;
    float4 ld[8];
#pragma unroll
    for (int j = 0; j < 8; ++j) ld[j] = *(const float4*)(ap + j * 4);
    short* dst = &As[sub][row * 264 + c0];
#pragma unroll
    for (int j = 0; j < 4; ++j)
      *(short8v*)(dst + j * 8) = pack8(ld[2 * j], ld[2 * j + 1]);
  }
  __syncthreads();

  f32x4 acc[2][4] = {};
  const short* wbase = Wp + (size_t)(wave * 64 + r) * 256;
#pragma unroll
  for (int ks = 0; ks < 8; ++ks) {
    short8v af0 = *(const short8v*)&As[sub][r * 264 + ks * 32 + g * 8];
    short8v af1 = *(const short8v*)&As[sub][(16 + r) * 264 + ks * 32 + g * 8];
    short8v bfr[4];
#pragma unroll
    for (int nf = 0; nf < 4; ++nf)
      bfr[nf] = *(const short8v*)(wbase + nf * 16 * 256 + ks * 32 + g * 8);
#pragma unroll
    for (int nf = 0; nf < 4; ++nf) {
      acc[0][nf] = __builtin_amdgcn_mfma_f32_16x16x32_bf16(af0, bfr[nf], acc[0][nf], 0, 0, 0);
      acc[1][nf] = __builtin_amdgcn_mfma_f32_16x16x32_bf16(af1, bfr[nf], acc[1][nf], 0, 0, 0);
    }
  }

#pragma unroll
  for (int mf = 0; mf < 2; ++mf)
#pragma unroll
    for (int nf = 0; nf < 4; ++nf) {
      int nn = wave * 64 + nf * 16 + r;
      float bval = bp[nn];
#pragma unroll
      for (int i = 0; i < 4; ++i) {
        int m = m0 + mf * 16 + g * 4 + i;
        if (m >= M) continue;
        Cb[(size_t)m * 256 + nn] = (short)f2bf((acc[mf][nf][i] + bval) * scale);
      }
    }
}

// ---------------- out-projection: (part0+part1) @ Wout^T + Bout ----------------
__global__ __launch_bounds__(512) void gemm512_out(
    const float* __restrict__ p0, const float* __restrict__ p1,
    const short* __restrict__ Wp, const float* __restrict__ bp,
    float* __restrict__ Cf) {
  __shared__ short As[2][32 * 264];
  const int M = 2400;
  int t = threadIdx.x, sub = t >> 8, u = t & 255;
  int wave = u >> 6, lane = u & 63, r = lane & 15, g = lane >> 4;
  int m0 = blockIdx.x * 64 + sub * 32;

  {
    int row = u >> 3, c0 = (u & 7) * 32;
    int mrow = m0 + row; if (mrow >= M) mrow = M - 1;
    size_t off = (size_t)mrow * 256 + c0;
    float4 ld[8];
#pragma unroll
    for (int j = 0; j < 8; ++j) {
      float4 x = *(const float4*)(p0 + off + j * 4);
      float4 y = *(const float4*)(p1 + off + j * 4);
      x.x += y.x; x.y += y.y; x.z += y.z; x.w += y.w;
      ld[j] = x;
    }
    short* dst = &As[sub][row * 264 + c0];
#pragma unroll
    for (int j = 0; j < 4; ++j)
      *(short8v*)(dst + j * 8) = pack8(ld[2 * j], ld[2 * j + 1]);
  }
  __syncthreads();

  f32x4 acc[2][4] = {};
  const short* wbase = Wp + (size_t)(wave * 64 + r) * 256;
#pragma unroll
  for (int ks = 0; ks < 8; ++ks) {
    short8v af0 = *(const short8v*)&As[sub][r * 264 + ks * 32 + g * 8];
    short8v af1 = *(const short8v*)&As[sub][(16 + r) * 264 + ks * 32 + g * 8];
    short8v bfr[4];
#pragma unroll
    for (int nf = 0; nf < 4; ++nf)
      bfr[nf] = *(const short8v*)(wbase + nf * 16 * 256 + ks * 32 + g * 8);
#pragma unroll
    for (int nf = 0; nf < 4; ++nf) {
      acc[0][nf] = __builtin_amdgcn_mfma_f32_16x16x32_bf16(af0, bfr[nf], acc[0][nf], 0, 0, 0);
      acc[1][nf] = __builtin_amdgcn_mfma_f32_16x16x32_bf16(af1, bfr[nf], acc[1][nf], 0, 0, 0);
    }
  }

#pragma unroll
  for (int mf = 0; mf < 2; ++mf)
#pragma unroll
    for (int nf = 0; nf < 4; ++nf) {
      int nn = wave * 64 + nf * 16 + r;
      float bval = bp[nn];
#pragma unroll
      for (int i = 0; i < 4; ++i) {
        int m = m0 + mf * 16 + g * 4 + i;
        if (m >= M) continue;
        int bb = m / 300, ll = m - bb * 300;
        Cf[((size_t)ll * 8 + bb) * 256 + nn] = acc[mf][nf][i] + bval;
      }
    }
}

// ---------------- scores + softmax: MFMA + in-register softmax ----------------
__global__ __launch_bounds__(64) void scores_softmax_v2(
    const short* __restrict__ qrb, const short* __restrict__ qcb,
    const short* __restrict__ krb, const short* __restrict__ kcb,
    short* __restrict__ wrowB, float* __restrict__ wcolT) {
  int lchunk = blockIdx.x, bn = blockIdx.y, kind = blockIdx.z;
  int b = bn >> 3, n = bn & 7;
  int lane = threadIdx.x;
  int r = lane & 15, g = lane >> 4;
  const short* qb = kind ? qcb : qrb;
  const short* kb = kind ? kcb : krb;
  int l0 = lchunk * 80;

  short8v a[5], bfr[6];
#pragma unroll
  for (int lf = 0; lf < 5; ++lf) {
    int l = l0 + lf * 16 + r;
    if (l > 299) l = 299;
    a[lf] = *(const short8v*)(qb + ((size_t)b * 300 + l) * 256 + n * 32 + g * 8);
  }
#pragma unroll
  for (int f = 0; f < 6; ++f)
    bfr[f] = *(const short8v*)(kb + ((size_t)b * 96 + f * 16 + r) * 256 + n * 32 + g * 8);

  f32x4 c[5][6];
#pragma unroll
  for (int lf = 0; lf < 5; ++lf)
#pragma unroll
    for (int f = 0; f < 6; ++f) {
      f32x4 z = {};
      c[lf][f] = __builtin_amdgcn_mfma_f32_16x16x32_bf16(a[lf], bfr[f], z, 0, 0, 0);
    }

#pragma unroll
  for (int lf = 0; lf < 5; ++lf)
#pragma unroll
    for (int i = 0; i < 4; ++i) {
      float m = c[lf][0][i];
#pragma unroll
      for (int f = 1; f < 6; ++f) m = fmaxf(m, c[lf][f][i]);
#pragma unroll
      for (int mask = 1; mask <= 8; mask <<= 1) m = fmaxf(m, __shfl_xor(m, mask, 64));
      float e[6], s = 0.f;
#pragma unroll
      for (int f = 0; f < 6; ++f) { e[f] = __expf(c[lf][f][i] - m); s += e[f]; }
#pragma unroll
      for (int mask = 1; mask <= 8; mask <<= 1) s += __shfl_xor(s, mask, 64);
      float inv = 1.f / s;
#pragma unroll
      for (int f = 0; f < 6; ++f) c[lf][f][i] = e[f] * inv;
    }

  if (kind == 0) {
#pragma unroll
    for (int lf = 0; lf < 5; ++lf)
#pragma unroll
      for (int i = 0; i < 4; ++i) {
        int l = l0 + lf * 16 + g * 4 + i;
        bool ok = (l < 300);
#pragma unroll
        for (int f = 0; f < 6; ++f) {
          float wv = ok ? c[lf][f][i] : 0.f;
          wrowB[((size_t)bn * 320 + l) * 96 + f * 16 + r] = (short)f2bf(wv);
        }
      }
  } else {
#pragma unroll
    for (int lf = 0; lf < 5; ++lf)
#pragma unroll
      for (int f = 0; f < 6; ++f) {
        int l = l0 + lf * 16 + g * 4;
        f32x4 wv = c[lf][f];
#pragma unroll
        for (int i = 0; i < 4; ++i) if (l + i >= 300) wv[i] = 0.f;
        *(f32x4*)(wcolT + ((size_t)bn * 96 + f * 16 + r) * 320 + l) = wv;
      }
  }
}

// ---------------- attention v5 (r20): r16 h-split + wcolT LDS-staged ----------
__global__ __launch_bounds__(512, 2) void attn_kernel(
    const short* __restrict__ wrowB, const float* __restrict__ wcolT,
    const short* __restrict__ vvT, float* __restrict__ part0,
    float* __restrict__ part1) {
  __shared__ f32x4 cmb[3][2][4][64];  // 24.6 KB
  __shared__ float wcs[48][64];       // 12.3 KB
  int i = blockIdx.x;
  int xcd = i & 7, j = i >> 3;          // j 0..79
  int grp = j / 10, rem = j - grp * 10;
  int bn = grp * 8 + xcd;               // all 10 blocks of a bn -> same XCD
  int lh = rem >> 1, hh2 = rem & 1;
  int b = bn >> 3, n = bn & 7;
  int t = threadIdx.x, wave = t >> 6, lane = t & 63;
  int df = wave & 1, hq = wave >> 1;    // hq 0..3, 12 h each
  int lbase = lh * 64;
  int r = lane & 15, g = lane >> 4;
  int hbase = hh2 * 48 + hq * 12;

  // stage wc slice (48 h x 64 l) once per block
  {
    const float* wsrc = wcolT + ((size_t)bn * 96 + hh2 * 48) * 320 + lbase;
#pragma unroll
    for (int k = 0; k < 2; ++k) {
      int u = t + k * 512;
      if (u < 768) {
        int row = u >> 4, cb = (u & 15) * 4;
        *(f32x4*)&wcs[row][cb] = *(const f32x4*)(wsrc + row * 320 + cb);
      }
    }
  }

  short8v a[4][3];
  const short* wr = wrowB + (size_t)bn * 320 * 96;
#pragma unroll
  for (int lf = 0; lf < 4; ++lf)
#pragma unroll
    for (int ks = 0; ks < 3; ++ks)
      a[lf][ks] = *(const short8v*)(wr + (lbase + lf * 16 + r) * 96 + ks * 32 + g * 8);

  const short* vb = vvT + (size_t)bn * 294912 + (size_t)(df * 16 + r) * 9216 + hbase * 96;
  __syncthreads();  // wcs ready

  f32x4 acc[4] = {};
  short8v b0[3], b1[3];
  int hl = hq * 12;
#pragma unroll
  for (int ks = 0; ks < 3; ++ks) b0[ks] = *(const short8v*)(vb + ks * 32 + g * 8);

#pragma unroll
  for (int h2 = 0; h2 < 6; ++h2) {
    int h = h2 * 2;
#pragma unroll
    for (int ks = 0; ks < 3; ++ks) b1[ks] = *(const short8v*)(vb + (h + 1) * 96 + ks * 32 + g * 8);
    {
      f32x4 R[4] = {};
#pragma unroll
      for (int ks = 0; ks < 3; ++ks)
#pragma unroll
        for (int lf = 0; lf < 4; ++lf)
          R[lf] = __builtin_amdgcn_mfma_f32_16x16x32_bf16(a[lf][ks], b0[ks], R[lf], 0, 0, 0);
#pragma unroll
      for (int lf = 0; lf < 4; ++lf) {
        f32x4 w = *(const f32x4*)&wcs[hl + h][lf * 16 + g * 4];
        acc[lf] += w * R[lf];
      }
    }
    if (h2 < 5) {
#pragma unroll
      for (int ks = 0; ks < 3; ++ks) b0[ks] = *(const short8v*)(vb + (h + 2) * 96 + ks * 32 + g * 8);
    }
    {
      f32x4 R[4] = {};
#pragma unroll
      for (int ks = 0; ks < 3; ++ks)
#pragma unroll
        for (int lf = 0; lf < 4; ++lf)
          R[lf] = __builtin_amdgcn_mfma_f32_16x16x32_bf16(a[lf][ks], b1[ks], R[lf], 0, 0, 0);
#pragma unroll
      for (int lf = 0; lf < 4; ++lf) {
        f32x4 w = *(const f32x4*)&wcs[hl + h + 1][lf * 16 + g * 4];
        acc[lf] += w * R[lf];
      }
    }
  }

  if (hq > 0) {
#pragma unroll
    for (int lf = 0; lf < 4; ++lf) cmb[hq - 1][df][lf][lane] = acc[lf];
  }
  __syncthreads();
  if (hq == 0) {
    float* po = hh2 ? part1 : part0;
#pragma unroll
    for (int lf = 0; lf < 4; ++lf) {
      f32x4 o = acc[lf];
#pragma unroll
      for (int q = 0; q < 3; ++q) o += cmb[q][df][lf][lane];
#pragma unroll
      for (int i2 = 0; i2 < 4; ++i2) {
        int l = lbase + lf * 16 + g * 4 + i2;
        if (l < 300)
          po[((size_t)b * 300 + l) * 256 + n * 32 + df * 16 + r] = o[i2];
      }
    }
  }
}

// ---------------- launch ----------------
extern "C" void kernel_launch(void* const* d_in, const int* in_sizes, int n_in,
                              void* d_out, int out_size, void* d_ws, size_t ws_size,
                              hipStream_t stream) {
  const float* query_row = (const float*)d_in[0];
  const float* query_col = (const float*)d_in[1];
  const float* key_row   = (const float*)d_in[2];
  const float* key_col   = (const float*)d_in[3];
  const float* value     = (const float*)d_in[4];
  const float* W         = (const float*)d_in[5];  // (1280,256)
  const float* Bv        = (const float*)d_in[6];  // (1280,)
  const float* Wout      = (const float*)d_in[7];  // (256,256)
  const float* Bout      = (const float*)d_in[8];  // (256,)

  float* ws = (float*)d_ws;
  float* krm   = ws;                        // 196608 f
  float* kcm   = krm + 196608;              // 196608 f
  float* part0 = kcm + 196608;              // 614400 f
  float* part1 = part0 + 614400;            // 614400 f
  float* wcolT = part1 + 614400;            // 1966080 f
  short* qrb   = (short*)(wcolT + 1966080); // 614400 s
  short* qcb   = qrb + 614400;              // 614400 s
  short* krb   = qcb + 614400;              // 196608 s
  short* kcb   = krb + 196608;              // 196608 s
  short* wrowB = kcb + 196608;              // 1966080 s
  short* vvT   = wrowB + 1966080;           // 18874368 s
  short* Wb    = vvT + 18874368;            // 393216 s

  means_kernel<<<960, 256, 0, stream>>>(key_row, key_col, krm, kcm, W, Wout, Wb);
  vproj_kernel<<<768, 512, 0, stream>>>(value, Wb + 262144, Bv + 1024, vvT);
  gemm512<<<100, 512, 0, stream>>>(krm, kcm, query_row, query_col, Wb, Bv,
                                   krb, kcb, qrb, qcb);
  scores_softmax_v2<<<dim3(4, 64, 2), 64, 0, stream>>>(qrb, qcb, krb, kcb, wrowB, wcolT);
  attn_kernel<<<640, 512, 0, stream>>>(wrowB, wcolT, vvT, part0, part1);
  gemm512_out<<<38, 512, 0, stream>>>(part0, part1, Wb + 327680, Bout, (float*)d_out);
}